// Round 8
// baseline (707.997 us; speedup 1.0000x reference)
//
#include <hip/hip_runtime.h>
#include <cstdint>
#include <cstddef>

// ---------------------------------------------------------------------------
// Problem constants
// ---------------------------------------------------------------------------
#define EMB   1024
#define TSEQ  2048
#define NBATCH 2
#define NHEAD 16
#define HDIM  64
#define VOCAB 32000
#define ROWS  4096          // B*T
#define NCB   125           // VOCAB / 256 column blocks

typedef __attribute__((ext_vector_type(8))) short short8;
typedef __attribute__((ext_vector_type(4))) float f32x4;

__device__ __forceinline__ unsigned short f2bf(float f) {
  unsigned int u = __float_as_uint(f);
  u = (u + 0x7FFFu + ((u >> 16) & 1u)) >> 16;   // RNE
  return (unsigned short)u;
}

__device__ __forceinline__ void gload16(const void* g, void* l) {
  typedef __attribute__((address_space(1))) const unsigned int gu;
  typedef __attribute__((address_space(3))) unsigned int lu;
  __builtin_amdgcn_global_load_lds((gu*)g, (lu*)l, 16, 0, 0);
}

// ---------------------------------------------------------------------------
// 1) f32 [R][C] -> bf16 [C][R] transpose-convert (weights)
// ---------------------------------------------------------------------------
__global__ void convT(const float* __restrict__ in, unsigned short* __restrict__ out,
                      int R, int C) {
  __shared__ float tile[32][33];
  const int ct = blockIdx.x, rt = blockIdx.y;
  const int t = threadIdx.x;
  const int r0 = t >> 5;          // 0..7
  const int c  = t & 31;
#pragma unroll
  for (int i = 0; i < 4; ++i) {
    int r = r0 + i * 8;
    tile[r][c] = in[(size_t)(rt * 32 + r) * C + ct * 32 + c];
  }
  __syncthreads();
#pragma unroll
  for (int i = 0; i < 4; ++i) {
    int r = r0 + i * 8;           // output row (= input col) within tile
    out[(size_t)(ct * 32 + r) * R + rt * 32 + c] = f2bf(tile[c][r]);
  }
}

// ---------------------------------------------------------------------------
// 2) h = tok_emb[x] + pos_emb  ->  bf16 [ROWS][EMB]
// ---------------------------------------------------------------------------
__global__ void embed_kernel(const int* __restrict__ x, const float* __restrict__ tok,
                             const float* __restrict__ pos, unsigned short* __restrict__ h) {
  const int idx = blockIdx.x * 256 + threadIdx.x;   // over ROWS * (EMB/4)
  const int row = idx >> 8;                         // EMB/4 = 256 groups per row
  const int c4  = idx & 255;
  const int tpos = row & (TSEQ - 1);
  const int token = x[row];
  float4 a = *(const float4*)(tok + (size_t)token * EMB + c4 * 4);
  float4 p = *(const float4*)(pos + (size_t)tpos * EMB + c4 * 4);
  unsigned int lo = (unsigned int)f2bf(a.x + p.x) | ((unsigned int)f2bf(a.y + p.y) << 16);
  unsigned int hi = (unsigned int)f2bf(a.z + p.z) | ((unsigned int)f2bf(a.w + p.w) << 16);
  *(uint2*)(h + (size_t)idx * 4) = make_uint2(lo, hi);
}

// ---------------------------------------------------------------------------
// 3) QKV GEMM (128x128 tile, m97-style). EPI=1: bf16 out scaled;
//    EPI=2: bf16 out transposed to Vt[b][h][d][t].
// ---------------------------------------------------------------------------
template <int EPI>
__global__ void gemm_bt(const unsigned short* __restrict__ A,
                        const unsigned short* __restrict__ Bt,
                        void* __restrict__ Cout,
                        float scale, int M, int N, int K) {
  __shared__ unsigned short As[2][128 * 32];
  __shared__ unsigned short Bs[2][128 * 32];
  const int t  = threadIdx.x;
  const int l  = t & 63;
  const int w  = t >> 6;
  const int wr = w >> 1, wc = w & 1;
  const int m0 = blockIdx.y * 128;
  const int n0 = blockIdx.x * 128;
  const int KT = K >> 5;

  f32x4 acc[4][4] = {};

  const int crow = t >> 2;
  const int coff = (t & 3) * 16;
  const size_t abase = ((size_t)(m0 + crow) * K) * 2 + coff;
  const size_t bbase = ((size_t)(n0 + crow) * K) * 2 + coff;
  const size_t rstep = (size_t)64 * K * 2;
  const char* Ab = (const char*)A;
  const char* Bb = (const char*)Bt;

#define STAGE(buf, kt_) do {                                              \
    size_t ko = (size_t)(kt_) * 64;                                       \
    gload16(Ab + abase + ko,         (char*)&As[(buf)][0] + t * 16);      \
    gload16(Ab + abase + rstep + ko, (char*)&As[(buf)][0] + t * 16 + 4096);\
    gload16(Bb + bbase + ko,         (char*)&Bs[(buf)][0] + t * 16);      \
    gload16(Bb + bbase + rstep + ko, (char*)&Bs[(buf)][0] + t * 16 + 4096);\
  } while (0)

  const int lr  = l & 15;
  const int lkb = (l >> 4) * 16;

#define COMPUTE(buf) do {                                                  \
    const char* ab = (const char*)&As[(buf)][0];                           \
    const char* bb = (const char*)&Bs[(buf)][0];                           \
    short8 fa[4], fb[4];                                                   \
    _Pragma("unroll")                                                      \
    for (int m = 0; m < 4; ++m)                                            \
      fa[m] = *(const short8*)(ab + (wr * 64 + m * 16 + lr) * 64 + lkb);   \
    _Pragma("unroll")                                                      \
    for (int n = 0; n < 4; ++n)                                            \
      fb[n] = *(const short8*)(bb + (wc * 64 + n * 16 + lr) * 64 + lkb);   \
    _Pragma("unroll")                                                      \
    for (int m = 0; m < 4; ++m)                                            \
      _Pragma("unroll")                                                    \
      for (int n = 0; n < 4; ++n)                                          \
        acc[m][n] = __builtin_amdgcn_mfma_f32_16x16x32_bf16(               \
            fa[m], fb[n], acc[m][n], 0, 0, 0);                             \
  } while (0)

  STAGE(0, 0);
  __syncthreads();
  int cur = 0;
  for (int kt = 0; kt < KT; ++kt) {
    if (kt + 1 < KT) STAGE(cur ^ 1, kt + 1);
    COMPUTE(cur);
    __syncthreads();
    cur ^= 1;
  }
#undef STAGE
#undef COMPUTE

  const int orow = m0 + wr * 64 + (l >> 4) * 4;
  const int ocol = n0 + wc * 64 + lr;
#pragma unroll
  for (int m = 0; m < 4; ++m) {
#pragma unroll
    for (int n = 0; n < 4; ++n) {
      const int col = ocol + n * 16;
      if (EPI == 1) {
        unsigned short* C = (unsigned short*)Cout;
#pragma unroll
        for (int r = 0; r < 4; ++r) {
          int row = orow + m * 16 + r;
          C[(size_t)row * N + col] = f2bf(acc[m][n][r] * scale);
        }
      } else {
        unsigned short* C = (unsigned short*)Cout;
        int row0 = orow + m * 16;
        int bb_ = row0 >> 11, tq = row0 & 2047;
        int hh = col >> 6, dd = col & 63;
        unsigned int lo = (unsigned int)f2bf(acc[m][n][0]) | ((unsigned int)f2bf(acc[m][n][1]) << 16);
        unsigned int hi = (unsigned int)f2bf(acc[m][n][2]) | ((unsigned int)f2bf(acc[m][n][3]) << 16);
        *(uint2*)&C[(((size_t)(bb_ * NHEAD + hh) * HDIM + dd) * TSEQ) + tq] = make_uint2(lo, hi);
      }
    }
  }
}

// ---------------------------------------------------------------------------
// 4) MFMA flash attention (bf16), unchanged (verified R2-R7).
// ---------------------------------------------------------------------------
__global__ __launch_bounds__(256)
void attn_mfma(const unsigned short* __restrict__ Qbf,
               const unsigned short* __restrict__ Kbf,
               const unsigned short* __restrict__ Vtbf,
               unsigned short* __restrict__ Obf) {
  const int qt = (gridDim.x - 1) - blockIdx.x;   // heavy tiles first
  const int h  = blockIdx.y;
  const int b  = blockIdx.z;
  const int t  = threadIdx.x, w = t >> 6, l = t & 63;
  const int g  = l >> 4, c = l & 15;
  const int qw = qt * 64 + w * 16;
  const int qg = qw + c;

  __shared__ unsigned short Ks[2][32 * 64];
  __shared__ unsigned short Vs[2][64 * 32];

  const unsigned short* Qrow = Qbf + ((size_t)(b * TSEQ + qg) * EMB + h * HDIM);
  short8 qfrag[2];
  qfrag[0] = *(const short8*)(Qrow + g * 8);
  qfrag[1] = *(const short8*)(Qrow + g * 8 + 32);

  f32x4 accO[4] = {};
  float mrun = -3e38f, lsum = 0.0f;

  const int kvt = t >> 3, kch = t & 7;
  const char* Kg = (const char*)(Kbf + ((size_t)(b * TSEQ + kvt) * EMB + h * HDIM))
                   + (((kch * 16) ^ ((kvt & 7) << 4)));
  const int dt = t >> 2, vch = t & 3;
  const char* Vg = (const char*)(Vtbf + (((size_t)(b * NHEAD + h) * HDIM + dt) * TSEQ))
                   + vch * 16;
  const size_t kstep = (size_t)32 * EMB * 2;
  const size_t vstep = (size_t)32 * 2;

#define ASTAGE(buf, kt_) do {                                               \
    gload16(Kg + (size_t)(kt_) * kstep, (char*)&Ks[buf][0] + t * 16);       \
    gload16(Vg + (size_t)(kt_) * vstep, (char*)&Vs[buf][0] + t * 16);       \
  } while (0)

  const int nkt = 2 * qt + 2;
  ASTAGE(0, 0);
  __syncthreads();
  int cur = 0;
  for (int kt = 0; kt < nkt; ++kt) {
    if (kt + 1 < nkt) ASTAGE(cur ^ 1, kt + 1);
    const int k0 = kt * 32;

    const char* kb = (const char*)&Ks[cur][0];
    f32x4 sa[2] = {};
#pragma unroll
    for (int kc = 0; kc < 2; ++kc) {
#pragma unroll
      for (int kh = 0; kh < 2; ++kh) {
        short8 ka = *(const short8*)(kb + (kc * 16 + c) * 128 +
                                     ((g * 16 + kh * 64) ^ ((c & 7) << 4)));
        sa[kc] = __builtin_amdgcn_mfma_f32_16x16x32_bf16(ka, qfrag[kh], sa[kc], 0, 0, 0);
      }
    }

    float sv[8];
#pragma unroll
    for (int kc = 0; kc < 2; ++kc)
#pragma unroll
      for (int r = 0; r < 4; ++r) {
        int kv = k0 + kc * 16 + g * 4 + r;
        sv[kc * 4 + r] = (kv > qg) ? -3e38f : sa[kc][r];
      }
    float pm = sv[0];
#pragma unroll
    for (int i = 1; i < 8; ++i) pm = fmaxf(pm, sv[i]);
    pm = fmaxf(pm, __shfl_xor(pm, 16));
    pm = fmaxf(pm, __shfl_xor(pm, 32));
    const float mnew = fmaxf(mrun, pm);
    const float alpha = __expf(mrun - mnew);
    float ps = 0.0f;
#pragma unroll
    for (int i = 0; i < 8; ++i) { float p = __expf(sv[i] - mnew); sv[i] = p; ps += p; }
    ps += __shfl_xor(ps, 16);
    ps += __shfl_xor(ps, 32);
    lsum = lsum * alpha + ps;
    mrun = mnew;

#pragma unroll
    for (int r = 0; r < 4; ++r) {
      float ar = __shfl(alpha, g * 4 + r);
      accO[0][r] *= ar; accO[1][r] *= ar; accO[2][r] *= ar; accO[3][r] *= ar;
    }

    unsigned int wf[4];
#pragma unroll
    for (int rp = 0; rp < 2; ++rp)
#pragma unroll
      for (int kc = 0; kc < 2; ++kc) {
        unsigned int rw;
        asm("v_cvt_pk_bf16_f32 %0, %1, %2"
            : "=v"(rw) : "v"(sv[kc * 4 + 2 * rp]), "v"(sv[kc * 4 + 2 * rp + 1]));
        wf[rp * 2 + kc] = rw;
      }

    union { unsigned int u[4]; short8 s8; } pa;
#pragma unroll
    for (int jp = 0; jp < 4; ++jp) {
      int srcLane = c + ((2 * (g & 1) + (jp >> 1)) << 4);
      unsigned int v0 = (unsigned int)__shfl((int)wf[2 * (jp & 1)], srcLane);
      unsigned int v1 = (unsigned int)__shfl((int)wf[2 * (jp & 1) + 1], srcLane);
      pa.u[jp] = (g >> 1) ? v1 : v0;
    }

    const char* vb = (const char*)&Vs[cur][0];
#pragma unroll
    for (int cp = 0; cp < 4; ++cp) {
      short8 vf = *(const short8*)(vb + (c + 16 * cp) * 64 + g * 16);
      accO[cp] = __builtin_amdgcn_mfma_f32_16x16x32_bf16(pa.s8, vf, accO[cp], 0, 0, 0);
    }

    __syncthreads();
    cur ^= 1;
  }
#undef ASTAGE

  const float inv = 1.0f / lsum;
#pragma unroll
  for (int r = 0; r < 4; ++r) {
    float ir = __shfl(inv, g * 4 + r);
    unsigned short* orow = Obf + ((size_t)(b * TSEQ + qw + g * 4 + r) * EMB + h * HDIM);
#pragma unroll
    for (int cp = 0; cp < 4; ++cp)
      orow[c + 16 * cp] = f2bf(accO[cp][r] * ir);
  }
}

// ---------------------------------------------------------------------------
// 5) LM-head GEMM: R7 kernel (K-loop, swizzle, stripe schedule byte-identical)
//    with ONE change: epilogue C-store is LDS-staged and instruction-coalesced
//    (4 quarter-passes [64][268] f32; each store = full wave x 16B = 1KB
//    contiguous; 32 dwordx4/thread replaces 128 dword/thread).
// ---------------------------------------------------------------------------
__global__ __launch_bounds__(512, 2)
void gemm_lm(const unsigned short* __restrict__ A,    // [4096][1024]
             const unsigned short* __restrict__ Bt,   // [32000][1024]
             const float* __restrict__ bias,
             float* __restrict__ C,
             float* __restrict__ pm, float* __restrict__ ps) {
  extern __shared__ char lds[];
  const int t = threadIdx.x;
  const int w = t >> 6, l = t & 63;
  const int wm = w >> 2, wn = w & 3;
  const int fr = l & 15, kg = l >> 4;

  // L2-resident stripe schedule (verified R7: FETCH 390->215MB)
  const int L  = blockIdx.x;
  const int Lp = (L & 7) * 250 + (L >> 3);   // XCD-contiguous Lp ranges
  const int g_ = Lp / 500;                    // stripe group of 4 mtiles
  const int q_ = Lp % 500;
  const int ntile = q_ >> 2;
  const int mtile = g_ * 4 + (q_ & 3);

  const char* Ag = (const char*)A;
  const char* Bg = (const char*)Bt;

  // staging precompute: thread covers LDS chunk ci=t (i=0) and 512+t (i=1)
  const int srow = t >> 3;              // chunk row 0..63
  const int scl  = t & 7;
  const int scg  = scl ^ (srow & 7);    // pre-swizzled global chunk
  size_t aoff0 = ((size_t)(mtile * 256 +       srow) * EMB) * 2 + scg * 16;
  size_t aoff1 = ((size_t)(mtile * 256 + 128 + srow) * EMB) * 2 + scg * 16;
  size_t boff0 = ((size_t)(ntile * 256 +       srow) * EMB) * 2 + scg * 16;
  size_t boff1 = ((size_t)(ntile * 256 + 128 + srow) * EMB) * 2 + scg * 16;

#define STG_A(buf_, kt_, ah_) do {                                          \
    char* d = lds + (buf_) * 65536 + (ah_) * 16384 + t * 16;                \
    const char* s = Ag + ((ah_) ? aoff1 : aoff0) + (size_t)(kt_) * 128;     \
    gload16(s, d); gload16(s + 131072, d + 8192);                           \
  } while (0)
#define STG_B(buf_, kt_, bh_) do {                                          \
    char* d = lds + (buf_) * 65536 + 32768 + (bh_) * 16384 + t * 16;        \
    const char* s = Bg + ((bh_) ? boff1 : boff0) + (size_t)(kt_) * 128;     \
    gload16(s, d); gload16(s + 131072, d + 8192);                           \
  } while (0)

  // ds_read fragment addressing (read-side applies the same xor)
  const int xr  = fr & 7;
  const int cb0 = (kg ^ xr) * 16;                 // ks=0 chunk byte; ks=1: ^64
  const int arow = (wm * 128 + fr) * 128;         // + mi*2048
  const int brow = (wn * 64 + fr) * 128;          // + ni*2048

  f32x4 acc[8][4] = {};
  short8 fa[4][2], fb[4][2];

#define MFMA_Q(MH, NH)                                                       \
  _Pragma("unroll")                                                          \
  for (int mi = 0; mi < 4; ++mi)                                             \
    _Pragma("unroll")                                                        \
    for (int ni = 0; ni < 2; ++ni)                                           \
      _Pragma("unroll")                                                      \
      for (int ks = 0; ks < 2; ++ks)                                         \
        acc[(MH)*4+mi][(NH)*2+ni] = __builtin_amdgcn_mfma_f32_16x16x32_bf16( \
            fa[mi][ks], fb[(NH)*2+ni][ks], acc[(MH)*4+mi][(NH)*2+ni], 0,0,0);

#define TILE(h_, S1, S2, VMN) do {                                           \
    const int buf_ = (h_) & 1;                                               \
    char* Abase = lds + buf_ * 65536;                                        \
    char* Bbase = Abase + 32768;                                             \
    /* ph1: q(0,0) */                                                        \
    _Pragma("unroll")                                                        \
    for (int mi = 0; mi < 4; ++mi) {                                         \
      fa[mi][0] = *(const short8*)(Abase + arow + mi*2048 + cb0);            \
      fa[mi][1] = *(const short8*)(Abase + arow + mi*2048 + (cb0^64));       \
    }                                                                        \
    _Pragma("unroll")                                                        \
    for (int ni = 0; ni < 2; ++ni) {                                         \
      fb[ni][0] = *(const short8*)(Bbase + brow + ni*2048 + cb0);            \
      fb[ni][1] = *(const short8*)(Bbase + brow + ni*2048 + (cb0^64));       \
    }                                                                        \
    if (S1) STG_A(buf_^1, (h_)+1, 0);                                        \
    __builtin_amdgcn_s_barrier();                                            \
    __builtin_amdgcn_s_setprio(1); MFMA_Q(0,0); __builtin_amdgcn_s_setprio(0);\
    __builtin_amdgcn_s_barrier();                                            \
    /* ph2: q(0,1) */                                                        \
    _Pragma("unroll")                                                        \
    for (int ni = 0; ni < 2; ++ni) {                                         \
      fb[2+ni][0] = *(const short8*)(Bbase + brow + (2+ni)*2048 + cb0);      \
      fb[2+ni][1] = *(const short8*)(Bbase + brow + (2+ni)*2048 + (cb0^64));  \
    }                                                                        \
    if (S1) STG_A(buf_^1, (h_)+1, 1);                                        \
    __builtin_amdgcn_s_barrier();                                            \
    __builtin_amdgcn_s_setprio(1); MFMA_Q(0,1); __builtin_amdgcn_s_setprio(0);\
    __builtin_amdgcn_s_barrier();                                            \
    /* ph3: q(1,1) */                                                        \
    _Pragma("unroll")                                                        \
    for (int mi = 0; mi < 4; ++mi) {                                         \
      fa[mi][0] = *(const short8*)(Abase + arow + (4+mi)*2048 + cb0);        \
      fa[mi][1] = *(const short8*)(Abase + arow + (4+mi)*2048 + (cb0^64));   \
    }                                                                        \
    if (S2) STG_B(buf_, (h_)+2, 0);                                          \
    __builtin_amdgcn_s_barrier();                                            \
    __builtin_amdgcn_s_setprio(1); MFMA_Q(1,1); __builtin_amdgcn_s_setprio(0);\
    __builtin_amdgcn_s_barrier();                                            \
    /* ph4: q(1,0) */                                                        \
    if (S2) STG_B(buf_, (h_)+2, 1);                                          \
    __builtin_amdgcn_s_barrier();                                            \
    __builtin_amdgcn_s_setprio(1); MFMA_Q(1,0); __builtin_amdgcn_s_setprio(0);\
    if (VMN) asm volatile("s_waitcnt vmcnt(4)" ::: "memory");                \
    else     asm volatile("s_waitcnt vmcnt(0)" ::: "memory");                \
    __builtin_amdgcn_s_barrier();                                            \
  } while (0)

  // prologue: tile0 all halves, tile1 B halves; wait tile0 landed
  STG_B(0, 0, 0); STG_B(0, 0, 1); STG_A(0, 0, 0); STG_A(0, 0, 1);
  STG_B(1, 1, 0); STG_B(1, 1, 1);
  asm volatile("s_waitcnt vmcnt(4)" ::: "memory");
  __builtin_amdgcn_s_barrier();

  for (int h = 0; h < 14; ++h) TILE(h, 1, 1, 4);
  TILE(14, 1, 0, 0);
  TILE(15, 0, 0, 0);
#undef TILE
#undef MFMA_Q
#undef STG_A
#undef STG_B

  __syncthreads();

  // ---- epilogue part 1: bias + fused loss partials ----
  const int mrow0 = mtile * 256 + wm * 128;
  const int ncol0 = ntile * 256 + wn * 64;
  float biasv[4];
#pragma unroll
  for (int ni = 0; ni < 4; ++ni) biasv[ni] = bias[ncol0 + ni * 16 + fr];
#pragma unroll
  for (int mi = 0; mi < 8; ++mi)
#pragma unroll
    for (int ni = 0; ni < 4; ++ni)
#pragma unroll
      for (int rr = 0; rr < 4; ++rr)
        acc[mi][ni][rr] += biasv[ni];

  float* redm = (float*)lds;             // [8][128]
  float* reds = (float*)(lds + 4096);    // [8][128]
#pragma unroll
  for (int mi = 0; mi < 8; ++mi)
#pragma unroll
    for (int rr = 0; rr < 4; ++rr) {
      float m1 = fmaxf(fmaxf(acc[mi][0][rr], acc[mi][1][rr]),
                       fmaxf(acc[mi][2][rr], acc[mi][3][rr]));
      m1 = fmaxf(m1, __shfl_xor(m1, 1));
      m1 = fmaxf(m1, __shfl_xor(m1, 2));
      m1 = fmaxf(m1, __shfl_xor(m1, 4));
      m1 = fmaxf(m1, __shfl_xor(m1, 8));
      if (fr == 0) redm[(wm * 4 + wn) * 128 + mi * 16 + kg * 4 + rr] = m1;
    }
  __syncthreads();

  float rmx[8][4];
#pragma unroll
  for (int mi = 0; mi < 8; ++mi)
#pragma unroll
    for (int rr = 0; rr < 4; ++rr) {
      int row = mi * 16 + kg * 4 + rr;
      float a0 = fmaxf(redm[(wm*4+0)*128 + row], redm[(wm*4+1)*128 + row]);
      float a1 = fmaxf(redm[(wm*4+2)*128 + row], redm[(wm*4+3)*128 + row]);
      rmx[mi][rr] = fmaxf(a0, a1);
    }
#pragma unroll
  for (int mi = 0; mi < 8; ++mi)
#pragma unroll
    for (int rr = 0; rr < 4; ++rr) {
      float r = rmx[mi][rr];
      float s1 = __expf(acc[mi][0][rr] - r) + __expf(acc[mi][1][rr] - r)
               + __expf(acc[mi][2][rr] - r) + __expf(acc[mi][3][rr] - r);
      s1 += __shfl_xor(s1, 1);
      s1 += __shfl_xor(s1, 2);
      s1 += __shfl_xor(s1, 4);
      s1 += __shfl_xor(s1, 8);
      if (fr == 0) reds[(wm * 4 + wn) * 128 + mi * 16 + kg * 4 + rr] = s1;
    }
  __syncthreads();

  if (wn == 0 && fr == 0) {
#pragma unroll
    for (int mi = 0; mi < 8; ++mi)
#pragma unroll
      for (int rr = 0; rr < 4; ++rr) {
        int row = mi * 16 + kg * 4 + rr;
        float ssum = reds[(wm*4+0)*128 + row] + reds[(wm*4+1)*128 + row]
                   + reds[(wm*4+2)*128 + row] + reds[(wm*4+3)*128 + row];
        int grow = mrow0 + row;
        pm[(size_t)grow * NCB + ntile] = rmx[mi][rr];
        ps[(size_t)grow * NCB + ntile] = ssum;
      }
  }
  __syncthreads();   // partials readers done before LDS reuse below

  // ---- epilogue part 2: LDS-staged instruction-coalesced C stores ----
  // 4 quarter-passes of [64 rows][268-padded f32] (68.6 KB). Writes: per
  // instruction 4 rows x 16 cols dword, row-stride 268 => kg groups offset
  // by 16 banks -> 2-way (free). Store pass: wave w covers ONE row per
  // instruction -> 64 lanes x 16B = 1KB contiguous global store.
  {
    float* eld = (float*)lds;
    const int erow8 = t >> 6;          // 0..7: row-within-pass
    const int ec4   = t & 63;          // 16B chunk within 256-col row
#pragma unroll
    for (int q = 0; q < 4; ++q) {
      if (wm == (q >> 1)) {
        const int mibase = (q & 1) * 4;
#pragma unroll
        for (int mi2 = 0; mi2 < 4; ++mi2)
#pragma unroll
          for (int rr = 0; rr < 4; ++rr) {
            const int row = mi2 * 16 + kg * 4 + rr;     // 0..63 in quarter
            const int colb = wn * 64 + fr;
#pragma unroll
            for (int ni = 0; ni < 4; ++ni)
              eld[row * 268 + colb + ni * 16] = acc[mibase + mi2][ni][rr];
          }
      }
      __syncthreads();
#pragma unroll
      for (int ps_ = 0; ps_ < 8; ++ps_) {
        const int row = ps_ * 8 + erow8;
        const int grow = mtile * 256 + q * 64 + row;
        f32x4 v = *(const f32x4*)(eld + row * 268 + ec4 * 4);
        *(f32x4*)(C + (size_t)grow * VOCAB + ntile * 256 + ec4 * 4) = v;
      }
      __syncthreads();
    }
  }
}

// ---------------------------------------------------------------------------
// 6) loss from partials: LSE over 125 (max,sumexp) pairs + target gather
// ---------------------------------------------------------------------------
__global__ void loss_rows2(const float* __restrict__ pm, const float* __restrict__ ps,
                           const float* __restrict__ logits, const int* __restrict__ tgt,
                           float* __restrict__ partial) {
  const int row = blockIdx.x * 4 + (threadIdx.x >> 6);
  const int l = threadIdx.x & 63;
  const float* pmr = pm + (size_t)row * NCB;
  const float* psr = ps + (size_t)row * NCB;
  float m = -3e38f, s = 0.0f;
  for (int i = l; i < NCB; i += 64) {
    float mv = pmr[i], sv = psr[i];
    float nm = fmaxf(m, mv);
    s = s * __expf(m - nm) + sv * __expf(mv - nm);
    m = nm;
  }
#pragma unroll
  for (int off = 1; off < 64; off <<= 1) {
    float om = __shfl_xor(m, off), os = __shfl_xor(s, off);
    float nm = fmaxf(m, om);
    s = s * __expf(m - nm) + os * __expf(om - nm);
    m = nm;
  }
  if (l == 0) {
    float lse = m + __logf(s);
    partial[row] = -(logits[(size_t)row * VOCAB + tgt[row]] - lse);
  }
}

__global__ void loss_final(const float* __restrict__ partial, float* __restrict__ out) {
  const int t = threadIdx.x;
  float s = 0.0f;
  for (int i = t; i < ROWS; i += 256) s += partial[i];
#pragma unroll
  for (int off = 1; off < 64; off <<= 1) s += __shfl_xor(s, off);
  __shared__ float ws_[4];
  if ((t & 63) == 0) ws_[t >> 6] = s;
  __syncthreads();
  if (t == 0) out[0] = (ws_[0] + ws_[1] + ws_[2] + ws_[3]) * (1.0f / (float)ROWS);
}

// ---------------------------------------------------------------------------
// launch
// ---------------------------------------------------------------------------
extern "C" void kernel_launch(void* const* d_in, const int* in_sizes, int n_in,
                              void* d_out, int out_size, void* d_ws, size_t ws_size,
                              hipStream_t stream) {
  const int*   x      = (const int*)d_in[0];
  const int*   target = (const int*)d_in[1];
  const float* tok    = (const float*)d_in[2];
  const float* pos    = (const float*)d_in[3];
  const float* Wq     = (const float*)d_in[4];
  const float* Wk     = (const float*)d_in[5];
  const float* Wv     = (const float*)d_in[6];
  const float* Wlm    = (const float*)d_in[7];
  const float* blm    = (const float*)d_in[8];
  float* out = (float*)d_out;

  char* p = (char*)d_ws;
  unsigned short* Wqt  = (unsigned short*)p; p += (size_t)EMB * EMB * 2;
  unsigned short* Wkt  = (unsigned short*)p; p += (size_t)EMB * EMB * 2;
  unsigned short* Wvt  = (unsigned short*)p; p += (size_t)EMB * EMB * 2;
  unsigned short* Wlmt = (unsigned short*)p; p += (size_t)VOCAB * EMB * 2;
  unsigned short* hbf  = (unsigned short*)p; p += (size_t)ROWS * EMB * 2;
  unsigned short* qbf  = (unsigned short*)p; p += (size_t)ROWS * EMB * 2;
  unsigned short* kbf  = (unsigned short*)p; p += (size_t)ROWS * EMB * 2;
  unsigned short* vtbf = (unsigned short*)p; p += (size_t)ROWS * EMB * 2;
  unsigned short* obf  = (unsigned short*)p; p += (size_t)ROWS * EMB * 2;
  float*          prt  = (float*)p;          p += (size_t)ROWS * 4;
  float*          pmw  = (float*)p;          p += (size_t)ROWS * NCB * 4;
  float*          psw  = (float*)p;          p += (size_t)ROWS * NCB * 4;

  (void)hipFuncSetAttribute((const void*)gemm_lm,
                            hipFuncAttributeMaxDynamicSharedMemorySize, 131072);

  dim3 b256(256);
  convT<<<dim3(EMB / 32, EMB / 32), b256, 0, stream>>>(Wq, Wqt, EMB, EMB);
  convT<<<dim3(EMB / 32, EMB / 32), b256, 0, stream>>>(Wk, Wkt, EMB, EMB);
  convT<<<dim3(EMB / 32, EMB / 32), b256, 0, stream>>>(Wv, Wvt, EMB, EMB);
  convT<<<dim3(VOCAB / 32, EMB / 32), b256, 0, stream>>>(Wlm, Wlmt, EMB, VOCAB);

  embed_kernel<<<ROWS * (EMB / 4) / 256, b256, 0, stream>>>(x, tok, pos, hbf);

  gemm_bt<1><<<dim3(EMB / 128, ROWS / 128), b256, 0, stream>>>(hbf, Wqt, qbf, 0.125f, ROWS, EMB, EMB);
  gemm_bt<1><<<dim3(EMB / 128, ROWS / 128), b256, 0, stream>>>(hbf, Wkt, kbf, 1.0f, ROWS, EMB, EMB);
  gemm_bt<2><<<dim3(EMB / 128, ROWS / 128), b256, 0, stream>>>(hbf, Wvt, vtbf, 1.0f, ROWS, EMB, EMB);

  attn_mfma<<<dim3(TSEQ / 64, NHEAD, NBATCH), b256, 0, stream>>>(qbf, kbf, vtbf, obf);

  gemm_lm<<<dim3((ROWS / 256) * (VOCAB / 256)), dim3(512), 131072, stream>>>(
      obf, Wlmt, blm, out, pmw, psw);

  loss_rows2<<<ROWS / 4, b256, 0, stream>>>(pmw, psw, out, target, prt);
  loss_final<<<1, b256, 0, stream>>>(prt, out + (size_t)ROWS * VOCAB);
}

// Round 9
// 600.014 us; speedup vs baseline: 1.1800x; 1.1800x over previous
//
#include <hip/hip_runtime.h>
#include <cstdint>
#include <cstddef>

// ---------------------------------------------------------------------------
// Problem constants
// ---------------------------------------------------------------------------
#define EMB   1024
#define TSEQ  2048
#define NBATCH 2
#define NHEAD 16
#define HDIM  64
#define VOCAB 32000
#define ROWS  4096          // B*T
#define NCB   125           // VOCAB / 256 column blocks

typedef __attribute__((ext_vector_type(8))) short short8;
typedef __attribute__((ext_vector_type(4))) float f32x4;

__device__ __forceinline__ unsigned short f2bf(float f) {
  unsigned int u = __float_as_uint(f);
  u = (u + 0x7FFFu + ((u >> 16) & 1u)) >> 16;   // RNE
  return (unsigned short)u;
}

__device__ __forceinline__ void gload16(const void* g, void* l) {
  typedef __attribute__((address_space(1))) const unsigned int gu;
  typedef __attribute__((address_space(3))) unsigned int lu;
  __builtin_amdgcn_global_load_lds((gu*)g, (lu*)l, 16, 0, 0);
}

// ---------------------------------------------------------------------------
// 1) f32 [R][C] -> bf16 [C][R] transpose-convert (weights)
// ---------------------------------------------------------------------------
__global__ void convT(const float* __restrict__ in, unsigned short* __restrict__ out,
                      int R, int C) {
  __shared__ float tile[32][33];
  const int ct = blockIdx.x, rt = blockIdx.y;
  const int t = threadIdx.x;
  const int r0 = t >> 5;          // 0..7
  const int c  = t & 31;
#pragma unroll
  for (int i = 0; i < 4; ++i) {
    int r = r0 + i * 8;
    tile[r][c] = in[(size_t)(rt * 32 + r) * C + ct * 32 + c];
  }
  __syncthreads();
#pragma unroll
  for (int i = 0; i < 4; ++i) {
    int r = r0 + i * 8;           // output row (= input col) within tile
    out[(size_t)(ct * 32 + r) * R + rt * 32 + c] = f2bf(tile[c][r]);
  }
}

// ---------------------------------------------------------------------------
// 2) h = tok_emb[x] + pos_emb  ->  bf16 [ROWS][EMB]
// ---------------------------------------------------------------------------
__global__ void embed_kernel(const int* __restrict__ x, const float* __restrict__ tok,
                             const float* __restrict__ pos, unsigned short* __restrict__ h) {
  const int idx = blockIdx.x * 256 + threadIdx.x;   // over ROWS * (EMB/4)
  const int row = idx >> 8;                         // EMB/4 = 256 groups per row
  const int c4  = idx & 255;
  const int tpos = row & (TSEQ - 1);
  const int token = x[row];
  float4 a = *(const float4*)(tok + (size_t)token * EMB + c4 * 4);
  float4 p = *(const float4*)(pos + (size_t)tpos * EMB + c4 * 4);
  unsigned int lo = (unsigned int)f2bf(a.x + p.x) | ((unsigned int)f2bf(a.y + p.y) << 16);
  unsigned int hi = (unsigned int)f2bf(a.z + p.z) | ((unsigned int)f2bf(a.w + p.w) << 16);
  *(uint2*)(h + (size_t)idx * 4) = make_uint2(lo, hi);
}

// ---------------------------------------------------------------------------
// 3) Fused QKV GEMM: C[4096, 3072] = h @ [Wq|Wk|Wv]^T (Wqt/Wkt/Wvt are
//    contiguous in ws => B is the stacked [3072][1024] matrix). 128x128 tile,
//    m97-style core (verified). Epilogue dispatch on col>>10:
//      sec 0 -> qbf (scaled 1/8), sec 1 -> kbf, sec 2 -> vtbf ([b][h][d][t]).
// ---------------------------------------------------------------------------
__global__ void gemm_qkv(const unsigned short* __restrict__ A,
                         const unsigned short* __restrict__ Bt,   // [3072][1024]
                         unsigned short* __restrict__ Qo,
                         unsigned short* __restrict__ Ko,
                         unsigned short* __restrict__ Vto) {
  __shared__ unsigned short As[2][128 * 32];
  __shared__ unsigned short Bs[2][128 * 32];
  const int K = EMB;
  const int t  = threadIdx.x;
  const int l  = t & 63;
  const int w  = t >> 6;
  const int wr = w >> 1, wc = w & 1;
  const int m0 = blockIdx.y * 128;
  const int n0 = blockIdx.x * 128;
  const int KT = K >> 5;

  f32x4 acc[4][4] = {};

  const int crow = t >> 2;
  const int coff = (t & 3) * 16;
  const size_t abase = ((size_t)(m0 + crow) * K) * 2 + coff;
  const size_t bbase = ((size_t)(n0 + crow) * K) * 2 + coff;
  const size_t rstep = (size_t)64 * K * 2;
  const char* Ab = (const char*)A;
  const char* Bb = (const char*)Bt;

#define STAGE(buf, kt_) do {                                              \
    size_t ko = (size_t)(kt_) * 64;                                       \
    gload16(Ab + abase + ko,         (char*)&As[(buf)][0] + t * 16);      \
    gload16(Ab + abase + rstep + ko, (char*)&As[(buf)][0] + t * 16 + 4096);\
    gload16(Bb + bbase + ko,         (char*)&Bs[(buf)][0] + t * 16);      \
    gload16(Bb + bbase + rstep + ko, (char*)&Bs[(buf)][0] + t * 16 + 4096);\
  } while (0)

  const int lr  = l & 15;
  const int lkb = (l >> 4) * 16;

#define COMPUTE(buf) do {                                                  \
    const char* ab = (const char*)&As[(buf)][0];                           \
    const char* bb = (const char*)&Bs[(buf)][0];                           \
    short8 fa[4], fb[4];                                                   \
    _Pragma("unroll")                                                      \
    for (int m = 0; m < 4; ++m)                                            \
      fa[m] = *(const short8*)(ab + (wr * 64 + m * 16 + lr) * 64 + lkb);   \
    _Pragma("unroll")                                                      \
    for (int n = 0; n < 4; ++n)                                            \
      fb[n] = *(const short8*)(bb + (wc * 64 + n * 16 + lr) * 64 + lkb);   \
    _Pragma("unroll")                                                      \
    for (int m = 0; m < 4; ++m)                                            \
      _Pragma("unroll")                                                    \
      for (int n = 0; n < 4; ++n)                                          \
        acc[m][n] = __builtin_amdgcn_mfma_f32_16x16x32_bf16(               \
            fa[m], fb[n], acc[m][n], 0, 0, 0);                             \
  } while (0)

  STAGE(0, 0);
  __syncthreads();
  int cur = 0;
  for (int kt = 0; kt < KT; ++kt) {
    if (kt + 1 < KT) STAGE(cur ^ 1, kt + 1);
    COMPUTE(cur);
    __syncthreads();
    cur ^= 1;
  }
#undef STAGE
#undef COMPUTE

  const int sec = n0 >> 10;            // 0:Q 1:K 2:V (block spans one section)
  const int orow = m0 + wr * 64 + (l >> 4) * 4;
  const int ocol = n0 + wc * 64 + lr;
#pragma unroll
  for (int m = 0; m < 4; ++m) {
#pragma unroll
    for (int n = 0; n < 4; ++n) {
      const int col = ocol + n * 16;
      const int c10 = col & 1023;
      if (sec == 0) {
#pragma unroll
        for (int r = 0; r < 4; ++r)
          Qo[(size_t)(orow + m * 16 + r) * EMB + c10] = f2bf(acc[m][n][r] * 0.125f);
      } else if (sec == 1) {
#pragma unroll
        for (int r = 0; r < 4; ++r)
          Ko[(size_t)(orow + m * 16 + r) * EMB + c10] = f2bf(acc[m][n][r]);
      } else {
        int row0 = orow + m * 16;
        int bb_ = row0 >> 11, tq = row0 & 2047;
        int hh = c10 >> 6, dd = c10 & 63;
        unsigned int lo = (unsigned int)f2bf(acc[m][n][0]) | ((unsigned int)f2bf(acc[m][n][1]) << 16);
        unsigned int hi = (unsigned int)f2bf(acc[m][n][2]) | ((unsigned int)f2bf(acc[m][n][3]) << 16);
        *(uint2*)&Vto[(((size_t)(bb_ * NHEAD + hh) * HDIM + dd) * TSEQ) + tq] = make_uint2(lo, hi);
      }
    }
  }
}

// ---------------------------------------------------------------------------
// 4) MFMA flash attention, KVBLK=64: one softmax max/exp/rescale/sync per
//    64 kv (was per 32). Per-32 fragment math identical to verified R2
//    kernel. K LDS xor-swizzled (as before); V LDS now also xor-swizzled
//    (read was 16-way bank conflict in [d][t] layout).
// ---------------------------------------------------------------------------
__global__ __launch_bounds__(256)
void attn_mfma(const unsigned short* __restrict__ Qbf,
               const unsigned short* __restrict__ Kbf,
               const unsigned short* __restrict__ Vtbf,
               unsigned short* __restrict__ Obf) {
  const int qt = (gridDim.x - 1) - blockIdx.x;   // heavy tiles first
  const int h  = blockIdx.y;
  const int b  = blockIdx.z;
  const int t  = threadIdx.x, w = t >> 6, l = t & 63;
  const int g  = l >> 4, c = l & 15;
  const int qw = qt * 64 + w * 16;
  const int qg = qw + c;

  __shared__ unsigned short Ks[2][64 * 64];   // [kv][d], 8KB
  __shared__ unsigned short Vs[2][64 * 64];   // [d][t],  8KB

  const unsigned short* Qrow = Qbf + ((size_t)(b * TSEQ + qg) * EMB + h * HDIM);
  short8 qfrag[2];
  qfrag[0] = *(const short8*)(Qrow + g * 8);
  qfrag[1] = *(const short8*)(Qrow + g * 8 + 32);

  f32x4 accO[4] = {};
  float mrun = -3e38f, lsum = 0.0f;

  // staging: 64 rows x 8 chunks of 16B per matrix; thread covers chunk pair
  // (t&3, (t&3)+4) of row t>>2, pre-swizzled (chunk ^= row&7).
  const int srw = t >> 2, sch = t & 3;
  const char* Kg = (const char*)(Kbf + ((size_t)(b * TSEQ + srw) * EMB + h * HDIM))
                   + ((sch ^ (srw & 7)) * 16);
  const char* Vg = (const char*)(Vtbf + (((size_t)(b * NHEAD + h) * HDIM + srw) * TSEQ))
                   + ((sch ^ (srw & 7)) * 16);
  const size_t kstep = (size_t)64 * EMB * 2;   // 64 kv rows
  const size_t vstep = (size_t)64 * 2;         // 64 t cols = 128B
  const int sdst = srw * 128 + sch * 16;

#define ASTAGE(buf, n_) do {                                                \
    const char* ks = Kg + (size_t)(n_) * kstep;                             \
    char* kd = (char*)&Ks[buf][0] + sdst;                                   \
    gload16(ks, kd);                                                        \
    gload16((const char*)((uintptr_t)ks ^ 64), kd + 64);                    \
    const char* vs = Vg + (size_t)(n_) * vstep;                             \
    char* vd = (char*)&Vs[buf][0] + sdst;                                   \
    gload16(vs, vd);                                                        \
    gload16((const char*)((uintptr_t)vs ^ 64), vd + 64);                    \
  } while (0)

  const int nkt = qt + 1;
  ASTAGE(0, 0);
  __syncthreads();
  int cur = 0;
  for (int n = 0; n < nkt; ++n) {
    if (n + 1 < nkt) ASTAGE(cur ^ 1, n + 1);
    const int k0 = n * 64;

    // ---- QK^T (swapped), both 32-kv halves ----
    const char* kb = (const char*)&Ks[cur][0];
    f32x4 sa[4];
#pragma unroll
    for (int hh = 0; hh < 2; ++hh)
#pragma unroll
      for (int kc = 0; kc < 2; ++kc) {
        f32x4 a0 = {};
#pragma unroll
        for (int kh = 0; kh < 2; ++kh) {
          short8 ka = *(const short8*)(kb + (hh * 32 + kc * 16 + c) * 128 +
                                       ((g * 16 + kh * 64) ^ ((c & 7) << 4)));
          a0 = __builtin_amdgcn_mfma_f32_16x16x32_bf16(ka, qfrag[kh], a0, 0, 0, 0);
        }
        sa[hh * 2 + kc] = a0;
      }

    // ---- single online softmax over 16 values ----
    float sv[16];
#pragma unroll
    for (int hh = 0; hh < 2; ++hh)
#pragma unroll
      for (int kc = 0; kc < 2; ++kc)
#pragma unroll
        for (int r = 0; r < 4; ++r) {
          int kv = k0 + hh * 32 + kc * 16 + g * 4 + r;
          sv[hh * 8 + kc * 4 + r] = (kv > qg) ? -3e38f : sa[hh * 2 + kc][r];
        }
    float pmax = sv[0];
#pragma unroll
    for (int i = 1; i < 16; ++i) pmax = fmaxf(pmax, sv[i]);
    pmax = fmaxf(pmax, __shfl_xor(pmax, 16));
    pmax = fmaxf(pmax, __shfl_xor(pmax, 32));
    const float mnew = fmaxf(mrun, pmax);
    const float alpha = __expf(mrun - mnew);
    float ps = 0.0f;
#pragma unroll
    for (int i = 0; i < 16; ++i) { float p = __expf(sv[i] - mnew); sv[i] = p; ps += p; }
    ps += __shfl_xor(ps, 16);
    ps += __shfl_xor(ps, 32);
    lsum = lsum * alpha + ps;
    mrun = mnew;
#pragma unroll
    for (int r = 0; r < 4; ++r) {
      float ar = __shfl(alpha, g * 4 + r);
      accO[0][r] *= ar; accO[1][r] *= ar; accO[2][r] *= ar; accO[3][r] *= ar;
    }

    // ---- per half: pack P, redistribute, PV ----
    const char* vb = (const char*)&Vs[cur][0];
#pragma unroll
    for (int hh = 0; hh < 2; ++hh) {
      unsigned int wf[4];
#pragma unroll
      for (int rp = 0; rp < 2; ++rp)
#pragma unroll
        for (int kc = 0; kc < 2; ++kc) {
          unsigned int rw;
          asm("v_cvt_pk_bf16_f32 %0, %1, %2"
              : "=v"(rw) : "v"(sv[hh * 8 + kc * 4 + 2 * rp]),
                           "v"(sv[hh * 8 + kc * 4 + 2 * rp + 1]));
          wf[rp * 2 + kc] = rw;
        }
      union { unsigned int u[4]; short8 s8; } pa;
#pragma unroll
      for (int jp = 0; jp < 4; ++jp) {
        int srcLane = c + ((2 * (g & 1) + (jp >> 1)) << 4);
        unsigned int v0 = (unsigned int)__shfl((int)wf[2 * (jp & 1)], srcLane);
        unsigned int v1 = (unsigned int)__shfl((int)wf[2 * (jp & 1) + 1], srcLane);
        pa.u[jp] = (g >> 1) ? v1 : v0;
      }
#pragma unroll
      for (int cp = 0; cp < 4; ++cp) {
        short8 vf = *(const short8*)(vb + (c + 16 * cp) * 128 +
                                     ((hh * 64 + g * 16) ^ ((c & 7) << 4)));
        accO[cp] = __builtin_amdgcn_mfma_f32_16x16x32_bf16(pa.s8, vf, accO[cp], 0, 0, 0);
      }
    }

    __syncthreads();
    cur ^= 1;
  }
#undef ASTAGE

  const float inv = 1.0f / lsum;
#pragma unroll
  for (int r = 0; r < 4; ++r) {
    float ir = __shfl(inv, g * 4 + r);
    unsigned short* orow = Obf + ((size_t)(b * TSEQ + qw + g * 4 + r) * EMB + h * HDIM);
#pragma unroll
    for (int cp = 0; cp < 4; ++cp)
      orow[c + 16 * cp] = f2bf(accO[cp][r] * ir);
  }
}

// ---------------------------------------------------------------------------
// 5) LM-head GEMM: exact R7 kernel (best measured: 417us).
// ---------------------------------------------------------------------------
__global__ __launch_bounds__(512, 2)
void gemm_lm(const unsigned short* __restrict__ A,    // [4096][1024]
             const unsigned short* __restrict__ Bt,   // [32000][1024]
             const float* __restrict__ bias,
             float* __restrict__ C,
             float* __restrict__ pm, float* __restrict__ ps) {
  extern __shared__ char lds[];
  const int t = threadIdx.x;
  const int w = t >> 6, l = t & 63;
  const int wm = w >> 2, wn = w & 3;
  const int fr = l & 15, kg = l >> 4;

  // L2-resident stripe schedule (verified R7: FETCH 390->215MB)
  const int L  = blockIdx.x;
  const int Lp = (L & 7) * 250 + (L >> 3);   // XCD-contiguous Lp ranges
  const int g_ = Lp / 500;                    // stripe group of 4 mtiles
  const int q_ = Lp % 500;
  const int ntile = q_ >> 2;
  const int mtile = g_ * 4 + (q_ & 3);

  const char* Ag = (const char*)A;
  const char* Bg = (const char*)Bt;

  const int srow = t >> 3;              // chunk row 0..63
  const int scl  = t & 7;
  const int scg  = scl ^ (srow & 7);    // pre-swizzled global chunk
  size_t aoff0 = ((size_t)(mtile * 256 +       srow) * EMB) * 2 + scg * 16;
  size_t aoff1 = ((size_t)(mtile * 256 + 128 + srow) * EMB) * 2 + scg * 16;
  size_t boff0 = ((size_t)(ntile * 256 +       srow) * EMB) * 2 + scg * 16;
  size_t boff1 = ((size_t)(ntile * 256 + 128 + srow) * EMB) * 2 + scg * 16;

#define STG_A(buf_, kt_, ah_) do {                                          \
    char* d = lds + (buf_) * 65536 + (ah_) * 16384 + t * 16;                \
    const char* s = Ag + ((ah_) ? aoff1 : aoff0) + (size_t)(kt_) * 128;     \
    gload16(s, d); gload16(s + 131072, d + 8192);                           \
  } while (0)
#define STG_B(buf_, kt_, bh_) do {                                          \
    char* d = lds + (buf_) * 65536 + 32768 + (bh_) * 16384 + t * 16;        \
    const char* s = Bg + ((bh_) ? boff1 : boff0) + (size_t)(kt_) * 128;     \
    gload16(s, d); gload16(s + 131072, d + 8192);                           \
  } while (0)

  const int xr  = fr & 7;
  const int cb0 = (kg ^ xr) * 16;                 // ks=0 chunk byte; ks=1: ^64
  const int arow = (wm * 128 + fr) * 128;         // + mi*2048
  const int brow = (wn * 64 + fr) * 128;          // + ni*2048

  f32x4 acc[8][4] = {};
  short8 fa[4][2], fb[4][2];

#define MFMA_Q(MH, NH)                                                       \
  _Pragma("unroll")                                                          \
  for (int mi = 0; mi < 4; ++mi)                                             \
    _Pragma("unroll")                                                        \
    for (int ni = 0; ni < 2; ++ni)                                           \
      _Pragma("unroll")                                                      \
      for (int ks = 0; ks < 2; ++ks)                                         \
        acc[(MH)*4+mi][(NH)*2+ni] = __builtin_amdgcn_mfma_f32_16x16x32_bf16( \
            fa[mi][ks], fb[(NH)*2+ni][ks], acc[(MH)*4+mi][(NH)*2+ni], 0,0,0);

#define TILE(h_, S1, S2, VMN) do {                                           \
    const int buf_ = (h_) & 1;                                               \
    char* Abase = lds + buf_ * 65536;                                        \
    char* Bbase = Abase + 32768;                                             \
    /* ph1: q(0,0) */                                                        \
    _Pragma("unroll")                                                        \
    for (int mi = 0; mi < 4; ++mi) {                                         \
      fa[mi][0] = *(const short8*)(Abase + arow + mi*2048 + cb0);            \
      fa[mi][1] = *(const short8*)(Abase + arow + mi*2048 + (cb0^64));       \
    }                                                                        \
    _Pragma("unroll")                                                        \
    for (int ni = 0; ni < 2; ++ni) {                                         \
      fb[ni][0] = *(const short8*)(Bbase + brow + ni*2048 + cb0);            \
      fb[ni][1] = *(const short8*)(Bbase + brow + ni*2048 + (cb0^64));       \
    }                                                                        \
    if (S1) STG_A(buf_^1, (h_)+1, 0);                                        \
    __builtin_amdgcn_s_barrier();                                            \
    __builtin_amdgcn_s_setprio(1); MFMA_Q(0,0); __builtin_amdgcn_s_setprio(0);\
    __builtin_amdgcn_s_barrier();                                            \
    /* ph2: q(0,1) */                                                        \
    _Pragma("unroll")                                                        \
    for (int ni = 0; ni < 2; ++ni) {                                         \
      fb[2+ni][0] = *(const short8*)(Bbase + brow + (2+ni)*2048 + cb0);      \
      fb[2+ni][1] = *(const short8*)(Bbase + brow + (2+ni)*2048 + (cb0^64));  \
    }                                                                        \
    if (S1) STG_A(buf_^1, (h_)+1, 1);                                        \
    __builtin_amdgcn_s_barrier();                                            \
    __builtin_amdgcn_s_setprio(1); MFMA_Q(0,1); __builtin_amdgcn_s_setprio(0);\
    __builtin_amdgcn_s_barrier();                                            \
    /* ph3: q(1,1) */                                                        \
    _Pragma("unroll")                                                        \
    for (int mi = 0; mi < 4; ++mi) {                                         \
      fa[mi][0] = *(const short8*)(Abase + arow + (4+mi)*2048 + cb0);        \
      fa[mi][1] = *(const short8*)(Abase + arow + (4+mi)*2048 + (cb0^64));   \
    }                                                                        \
    if (S2) STG_B(buf_, (h_)+2, 0);                                          \
    __builtin_amdgcn_s_barrier();                                            \
    __builtin_amdgcn_s_setprio(1); MFMA_Q(1,1); __builtin_amdgcn_s_setprio(0);\
    __builtin_amdgcn_s_barrier();                                            \
    /* ph4: q(1,0) */                                                        \
    if (S2) STG_B(buf_, (h_)+2, 1);                                          \
    __builtin_amdgcn_s_barrier();                                            \
    __builtin_amdgcn_s_setprio(1); MFMA_Q(1,0); __builtin_amdgcn_s_setprio(0);\
    if (VMN) asm volatile("s_waitcnt vmcnt(4)" ::: "memory");                \
    else     asm volatile("s_waitcnt vmcnt(0)" ::: "memory");                \
    __builtin_amdgcn_s_barrier();                                            \
  } while (0)

  STG_B(0, 0, 0); STG_B(0, 0, 1); STG_A(0, 0, 0); STG_A(0, 0, 1);
  STG_B(1, 1, 0); STG_B(1, 1, 1);
  asm volatile("s_waitcnt vmcnt(4)" ::: "memory");
  __builtin_amdgcn_s_barrier();

  for (int h = 0; h < 14; ++h) TILE(h, 1, 1, 4);
  TILE(14, 1, 0, 0);
  TILE(15, 0, 0, 0);
#undef TILE
#undef MFMA_Q
#undef STG_A
#undef STG_B

  __syncthreads();

  // ---- epilogue: bias + logits write + fused loss partials ----
  const int mrow0 = mtile * 256 + wm * 128;
  const int ncol0 = ntile * 256 + wn * 64;
  float biasv[4];
#pragma unroll
  for (int ni = 0; ni < 4; ++ni) biasv[ni] = bias[ncol0 + ni * 16 + fr];
#pragma unroll
  for (int mi = 0; mi < 8; ++mi)
#pragma unroll
    for (int ni = 0; ni < 4; ++ni)
#pragma unroll
      for (int rr = 0; rr < 4; ++rr)
        acc[mi][ni][rr] += biasv[ni];

#pragma unroll
  for (int mi = 0; mi < 8; ++mi)
#pragma unroll
    for (int rr = 0; rr < 4; ++rr) {
      int row = mrow0 + mi * 16 + kg * 4 + rr;
      float* cr = C + (size_t)row * VOCAB + ncol0 + fr;
#pragma unroll
      for (int ni = 0; ni < 4; ++ni) cr[ni * 16] = acc[mi][ni][rr];
    }

  float* redm = (float*)lds;             // [8][128]
  float* reds = (float*)(lds + 4096);    // [8][128]
#pragma unroll
  for (int mi = 0; mi < 8; ++mi)
#pragma unroll
    for (int rr = 0; rr < 4; ++rr) {
      float m1 = fmaxf(fmaxf(acc[mi][0][rr], acc[mi][1][rr]),
                       fmaxf(acc[mi][2][rr], acc[mi][3][rr]));
      m1 = fmaxf(m1, __shfl_xor(m1, 1));
      m1 = fmaxf(m1, __shfl_xor(m1, 2));
      m1 = fmaxf(m1, __shfl_xor(m1, 4));
      m1 = fmaxf(m1, __shfl_xor(m1, 8));
      if (fr == 0) redm[(wm * 4 + wn) * 128 + mi * 16 + kg * 4 + rr] = m1;
    }
  __syncthreads();

  float rmx[8][4];
#pragma unroll
  for (int mi = 0; mi < 8; ++mi)
#pragma unroll
    for (int rr = 0; rr < 4; ++rr) {
      int row = mi * 16 + kg * 4 + rr;
      float a0 = fmaxf(redm[(wm*4+0)*128 + row], redm[(wm*4+1)*128 + row]);
      float a1 = fmaxf(redm[(wm*4+2)*128 + row], redm[(wm*4+3)*128 + row]);
      rmx[mi][rr] = fmaxf(a0, a1);
    }
#pragma unroll
  for (int mi = 0; mi < 8; ++mi)
#pragma unroll
    for (int rr = 0; rr < 4; ++rr) {
      float r = rmx[mi][rr];
      float s1 = __expf(acc[mi][0][rr] - r) + __expf(acc[mi][1][rr] - r)
               + __expf(acc[mi][2][rr] - r) + __expf(acc[mi][3][rr] - r);
      s1 += __shfl_xor(s1, 1);
      s1 += __shfl_xor(s1, 2);
      s1 += __shfl_xor(s1, 4);
      s1 += __shfl_xor(s1, 8);
      if (fr == 0) reds[(wm * 4 + wn) * 128 + mi * 16 + kg * 4 + rr] = s1;
    }
  __syncthreads();

  if (wn == 0 && fr == 0) {
#pragma unroll
    for (int mi = 0; mi < 8; ++mi)
#pragma unroll
      for (int rr = 0; rr < 4; ++rr) {
        int row = mi * 16 + kg * 4 + rr;
        float ssum = reds[(wm*4+0)*128 + row] + reds[(wm*4+1)*128 + row]
                   + reds[(wm*4+2)*128 + row] + reds[(wm*4+3)*128 + row];
        int grow = mrow0 + row;
        pm[(size_t)grow * NCB + ntile] = rmx[mi][rr];
        ps[(size_t)grow * NCB + ntile] = ssum;
      }
  }
}

// ---------------------------------------------------------------------------
// 6) loss from partials: LSE over 125 (max,sumexp) pairs + target gather
// ---------------------------------------------------------------------------
__global__ void loss_rows2(const float* __restrict__ pm, const float* __restrict__ ps,
                           const float* __restrict__ logits, const int* __restrict__ tgt,
                           float* __restrict__ partial) {
  const int row = blockIdx.x * 4 + (threadIdx.x >> 6);
  const int l = threadIdx.x & 63;
  const float* pmr = pm + (size_t)row * NCB;
  const float* psr = ps + (size_t)row * NCB;
  float m = -3e38f, s = 0.0f;
  for (int i = l; i < NCB; i += 64) {
    float mv = pmr[i], sv = psr[i];
    float nm = fmaxf(m, mv);
    s = s * __expf(m - nm) + sv * __expf(mv - nm);
    m = nm;
  }
#pragma unroll
  for (int off = 1; off < 64; off <<= 1) {
    float om = __shfl_xor(m, off), os = __shfl_xor(s, off);
    float nm = fmaxf(m, om);
    s = s * __expf(m - nm) + os * __expf(om - nm);
    m = nm;
  }
  if (l == 0) {
    float lse = m + __logf(s);
    partial[row] = -(logits[(size_t)row * VOCAB + tgt[row]] - lse);
  }
}

__global__ void loss_final(const float* __restrict__ partial, float* __restrict__ out) {
  const int t = threadIdx.x;
  float s = 0.0f;
  for (int i = t; i < ROWS; i += 256) s += partial[i];
#pragma unroll
  for (int off = 1; off < 64; off <<= 1) s += __shfl_xor(s, off);
  __shared__ float ws_[4];
  if ((t & 63) == 0) ws_[t >> 6] = s;
  __syncthreads();
  if (t == 0) out[0] = (ws_[0] + ws_[1] + ws_[2] + ws_[3]) * (1.0f / (float)ROWS);
}

// ---------------------------------------------------------------------------
// launch
// ---------------------------------------------------------------------------
extern "C" void kernel_launch(void* const* d_in, const int* in_sizes, int n_in,
                              void* d_out, int out_size, void* d_ws, size_t ws_size,
                              hipStream_t stream) {
  const int*   x      = (const int*)d_in[0];
  const int*   target = (const int*)d_in[1];
  const float* tok    = (const float*)d_in[2];
  const float* pos    = (const float*)d_in[3];
  const float* Wq     = (const float*)d_in[4];
  const float* Wk     = (const float*)d_in[5];
  const float* Wv     = (const float*)d_in[6];
  const float* Wlm    = (const float*)d_in[7];
  const float* blm    = (const float*)d_in[8];
  float* out = (float*)d_out;

  char* p = (char*)d_ws;
  unsigned short* Wqt  = (unsigned short*)p; p += (size_t)EMB * EMB * 2;
  unsigned short* Wkt  = (unsigned short*)p; p += (size_t)EMB * EMB * 2;
  unsigned short* Wvt  = (unsigned short*)p; p += (size_t)EMB * EMB * 2;
  unsigned short* Wlmt = (unsigned short*)p; p += (size_t)VOCAB * EMB * 2;
  unsigned short* hbf  = (unsigned short*)p; p += (size_t)ROWS * EMB * 2;
  unsigned short* qbf  = (unsigned short*)p; p += (size_t)ROWS * EMB * 2;
  unsigned short* kbf  = (unsigned short*)p; p += (size_t)ROWS * EMB * 2;
  unsigned short* vtbf = (unsigned short*)p; p += (size_t)ROWS * EMB * 2;
  unsigned short* obf  = (unsigned short*)p; p += (size_t)ROWS * EMB * 2;
  float*          prt  = (float*)p;          p += (size_t)ROWS * 4;
  float*          pmw  = (float*)p;          p += (size_t)ROWS * NCB * 4;
  float*          psw  = (float*)p;          p += (size_t)ROWS * NCB * 4;

  (void)hipFuncSetAttribute((const void*)gemm_lm,
                            hipFuncAttributeMaxDynamicSharedMemorySize, 131072);

  dim3 b256(256);
  convT<<<dim3(EMB / 32, EMB / 32), b256, 0, stream>>>(Wq, Wqt, EMB, EMB);
  convT<<<dim3(EMB / 32, EMB / 32), b256, 0, stream>>>(Wk, Wkt, EMB, EMB);
  convT<<<dim3(EMB / 32, EMB / 32), b256, 0, stream>>>(Wv, Wvt, EMB, EMB);
  convT<<<dim3(VOCAB / 32, EMB / 32), b256, 0, stream>>>(Wlm, Wlmt, EMB, VOCAB);

  embed_kernel<<<ROWS * (EMB / 4) / 256, b256, 0, stream>>>(x, tok, pos, hbf);

  // fused QKV: B = stacked [Wqt|Wkt|Wvt] (contiguous in ws)
  gemm_qkv<<<dim3(3 * EMB / 128, ROWS / 128), b256, 0, stream>>>(hbf, Wqt, qbf, kbf, vtbf);

  attn_mfma<<<dim3(TSEQ / 64, NHEAD, NBATCH), b256, 0, stream>>>(qbf, kbf, vtbf, obf);

  gemm_lm<<<dim3((ROWS / 256) * (VOCAB / 256)), dim3(512), 131072, stream>>>(
      obf, Wlmt, blm, out, pmw, psw);

  loss_rows2<<<ROWS / 4, b256, 0, stream>>>(pmw, psw, out, target, prt);
  loss_final<<<1, b256, 0, stream>>>(prt, out + (size_t)ROWS * VOCAB);
}